// Round 9
// baseline (226.760 us; speedup 1.0000x reference)
//
#include <hip/hip_runtime.h>

typedef unsigned int u32;
typedef int i32x4 __attribute__((ext_vector_type(4)));

#define DIN 2048              // K elements; int8 row = 2048 bytes
#define DOUT 8192
#define MROWS 8192            // B*S
#define NELEM_W (8192 * 2048)
#define NT 16                 // K-tiles of 128 int8

// workspace layout (bytes)
#define WS_PART 0                        // double[2048]
#define WS_WFAC 16384                    // float
#define WS_ROWFAC 16640                  // float[8192]
#define WS_XQ 49408                      // int8[8192*2048]
#define WS_WQ (49408 + 16777216)         // int8[8192*2048]

// ---------------- weight abs-sum (stage 1) ----------------------------------
__global__ void k_wabs(const float* __restrict__ w, double* __restrict__ part) {
    const float4* w4 = (const float4*)w;
    const unsigned t = threadIdx.x, b = blockIdx.x;
    float s = 0.f;
    for (unsigned i = b * 256u + t; i < (NELEM_W / 4); i += 2048u * 256u) {
        float4 v = w4[i];
        s += fabsf(v.x) + fabsf(v.y) + fabsf(v.z) + fabsf(v.w);
    }
    double d = (double)s;
    #pragma unroll
    for (int o = 32; o; o >>= 1) d += __shfl_down(d, o);
    __shared__ double red[4];
    if ((t & 63u) == 0u) red[t >> 6] = d;
    __syncthreads();
    if (t == 0) part[b] = red[0] + red[1] + red[2] + red[3];
}

// ---------------- weight abs-mean (stage 2) ---------------------------------
__global__ void k_wfin(const double* __restrict__ part, float* __restrict__ wfac) {
    const int t = threadIdx.x;
    double s = 0.0;
    #pragma unroll
    for (int j = 0; j < 8; ++j) s += part[t + j * 256];
    #pragma unroll
    for (int o = 32; o; o >>= 1) s += __shfl_down(s, o);
    __shared__ double red[4];
    if ((t & 63) == 0) red[t >> 6] = s;
    __syncthreads();
    if (t == 0) {
        double mean = (red[0] + red[1] + red[2] + red[3]) * (1.0 / (double)NELEM_W);
        *wfac = fmaxf((float)mean, 1e-5f);
    }
}

// ---------------- fused: ternary weight quant + RMS-norm/act quant ----------
__global__ void k_prep(const float* __restrict__ w, const float* __restrict__ wfac,
                       u32* __restrict__ wq, const float* __restrict__ x,
                       u32* __restrict__ xq, float* __restrict__ rowfac) {
    const int t = threadIdx.x;
    if (blockIdx.x < 2048) {
        const float scale = 1.0f / *wfac;
        const float4* w4 = (const float4*)w;
        for (unsigned i = blockIdx.x * 256u + t; i < (NELEM_W / 4); i += 2048u * 256u) {
            float4 v = w4[i];
            int q0 = (int)fminf(fmaxf(rintf(v.x * scale), -1.f), 1.f);
            int q1 = (int)fminf(fmaxf(rintf(v.y * scale), -1.f), 1.f);
            int q2 = (int)fminf(fmaxf(rintf(v.z * scale), -1.f), 1.f);
            int q3 = (int)fminf(fmaxf(rintf(v.w * scale), -1.f), 1.f);
            wq[i] = (u32)(q0 & 255) | ((u32)(q1 & 255) << 8) |
                    ((u32)(q2 & 255) << 16) | ((u32)(q3 & 255) << 24);
        }
        return;
    }
    const int row = blockIdx.x - 2048;
    const float4* xr = (const float4*)(x + (size_t)row * DIN);
    float4 v0 = xr[t], v1 = xr[t + 256];
    float ss = v0.x * v0.x + v0.y * v0.y + v0.z * v0.z + v0.w * v0.w
             + v1.x * v1.x + v1.y * v1.y + v1.z * v1.z + v1.w * v1.w;
    __shared__ float red[4];
    #pragma unroll
    for (int o = 32; o; o >>= 1) ss += __shfl_down(ss, o);
    if ((t & 63) == 0) red[t >> 6] = ss;
    __syncthreads();
    ss = red[0] + red[1] + red[2] + red[3];
    const float r = 1.0f / sqrtf(ss * (1.0f / DIN) + 1.1920929e-7f);
    float xn[8] = {v0.x * r, v0.y * r, v0.z * r, v0.w * r,
                   v1.x * r, v1.y * r, v1.z * r, v1.w * r};
    float am = 0.f;
    #pragma unroll
    for (int j = 0; j < 8; ++j) am = fmaxf(am, fabsf(xn[j]));
    __syncthreads();
    #pragma unroll
    for (int o = 32; o; o >>= 1) am = fmaxf(am, __shfl_down(am, o));
    if ((t & 63) == 0) red[t >> 6] = am;
    __syncthreads();
    am = fmaxf(fmaxf(red[0], red[1]), fmaxf(red[2], red[3]));
    const float amc = fmaxf(am, 1e-5f);
    const float s = 127.0f / amc;
    int q[8];
    #pragma unroll
    for (int j = 0; j < 8; ++j)
        q[j] = (int)fminf(fmaxf(rintf(xn[j] * s), -128.f), 127.f);
    u32* xo = xq + (size_t)row * (DIN / 4);
    xo[t] = (u32)(q[0] & 255) | ((u32)(q[1] & 255) << 8) |
            ((u32)(q[2] & 255) << 16) | ((u32)(q[3] & 255) << 24);
    xo[t + 256] = (u32)(q[4] & 255) | ((u32)(q[5] & 255) << 8) |
                  ((u32)(q[6] & 255) << 16) | ((u32)(q[7] & 255) << 24);
    if (t == 0) rowfac[row] = amc * (1.0f / 127.0f);
}

// ---------------- persistent 256x256 int8 GEMM, within-wave pipelined --------
// Grid = 256 blocks (1/CU), 4 output tiles each (2x2 zigzag, XCD-partitioned).
// LDS: A[slot][kh][256][64B] @0, B same @+65536 (slot 32768, kh 16384).
// r3's VERIFIED zero-conflict swizzle: read granule = lc ^ ((row>>1)&3);
// staged via inverse perm on global source (rule #21).
// Per K-tile (slot s, other o), 4 groups; each group's ds_reads feed the
// NEXT group's MFMA so reads drain under MFMA (compiler counted lgkmcnt):
//   g1: rd A(s,kh0,m4-7), B(s,kh1);  MFMA(kh0,m0-3)
//   g2: rd A(s,kh1,m0-3);            MFMA(kh0,m4-7)
//   g3: rd A(s,kh1,m4-7);            MFMA(kh1,m0-3)
//   LGKM0; BAR; STG(T+2 -> s); VM(8); BAR
//   g4: rd A(o,kh0,m0-3), B(o,kh0);  MFMA(kh1,m4-7)   // T+1 preload
// 2 barriers + 1 counted gate per tile; never vmcnt(0) mid-stream.
__launch_bounds__(512, 2)
__global__ void k_gemm(const char* __restrict__ A, const char* __restrict__ Bw,
                       const float* __restrict__ rowfac, const float* __restrict__ wfac,
                       float* __restrict__ out) {
    __shared__ __attribute__((aligned(16))) char smb[131072];

    const int t = threadIdx.x;
    const int l = t & 63, w = t >> 6;
    const int wm = w >> 2, wn = w & 3;
    const int lr = l & 15, lc = l >> 4;
    // r3 verified: 2 lanes/bank-quad on opposite row parity -> 0 conflicts
    const int laneF = lr * 64 + ((lc ^ ((lr >> 1) & 3)) * 16);

    // persistent tile mapping: block -> XCD-contiguous 2x2 super-tile
    const int bid = blockIdx.x;            // 0..255
    const int xcd = bid & 7, idx = bid >> 3;
    const int st = xcd * 32 + idx;
    const int sm = st >> 4, sn = st & 15;

    const float wf = *wfac;

// stage one (operand, kh) half: 2 gload_lds per thread (r3 verbatim)
#define STAGE(gbase, opOff, tB, kh, s) do {                                       \
    _Pragma("unroll")                                                             \
    for (int j_ = 0; j_ < 2; ++j_) {                                              \
        const int seg_ = w * 2 + j_;                                              \
        const int row_ = seg_ * 16 + (l >> 2);                                    \
        const int sc_ = (l & 3) ^ ((l >> 3) & 3);                                 \
        const char* src_ = (gbase) + (size_t)row_ * DIN + (tB) + (kh) * 64 + sc_ * 16; \
        __builtin_amdgcn_global_load_lds(                                         \
            (const __attribute__((address_space(1))) void*)src_,                  \
            (__attribute__((address_space(3))) void*)(smb + (opOff) + (s) * 32768 + (kh) * 16384 + seg_ * 1024), \
            16, 0, 0);                                                            \
    }                                                                             \
} while (0)

// full-tile stage: 8 gload_lds per thread (FIFO count = 8)
#define STGT(tB, s) do {                                                          \
    STAGE(Ab, 0,     (tB), 0, (s));                                               \
    STAGE(Bb, 65536, (tB), 0, (s));                                               \
    STAGE(Ab, 0,     (tB), 1, (s));                                               \
    STAGE(Bb, 65536, (tB), 1, (s));                                               \
} while (0)

#define RDA(s, kh, mB, dst) do {                                                  \
    _Pragma("unroll")                                                             \
    for (int i_ = 0; i_ < 4; ++i_)                                                \
        dst[i_] = *(const i32x4*)(smb + (s) * 32768 + (kh) * 16384 +              \
                                  (wm * 128 + ((mB) + i_) * 16) * 64 + laneF);    \
} while (0)

#define RDB(s, kh, dst) do {                                                      \
    _Pragma("unroll")                                                             \
    for (int n_ = 0; n_ < 4; ++n_)                                                \
        dst[n_] = *(const i32x4*)(smb + 65536 + (s) * 32768 + (kh) * 16384 +      \
                                  (wn * 64 + n_ * 16) * 64 + laneF);              \
} while (0)

#define MFMA16(mB, fA, fB) do {                                                   \
    __builtin_amdgcn_s_setprio(1);                                                \
    _Pragma("unroll")                                                             \
    for (int i_ = 0; i_ < 4; ++i_)                                                \
        _Pragma("unroll")                                                         \
        for (int n_ = 0; n_ < 4; ++n_)                                            \
            acc[(mB) + i_][n_] = __builtin_amdgcn_mfma_i32_16x16x64_i8(           \
                fA[i_], fB[n_], acc[(mB) + i_][n_], 0, 0, 0);                     \
    __builtin_amdgcn_s_setprio(0);                                                \
} while (0)

#define LGKM0 asm volatile("s_waitcnt lgkmcnt(0)" ::: "memory")
#define VM(n) asm volatile("s_waitcnt vmcnt(" #n ")" ::: "memory")
#define BAR __builtin_amdgcn_s_barrier()

// one K-tile: s = this tile's slot, o = other slot (T+1), STG_STMT stages T+2,
// GATE_STMT = VM(8) normally / VM(0) for the penultimate tile.
#define TILE(s, o, STG_STMT, GATE_STMT) do {                                      \
    RDA(s, 0, 4, fa2);                                                            \
    RDB(s, 1, fb2);                                                               \
    MFMA16(0, fa, fb);          /* kh0 m0-3 */                                    \
    RDA(s, 1, 0, fa);                                                             \
    MFMA16(4, fa2, fb);         /* kh0 m4-7 */                                    \
    RDA(s, 1, 4, fa2);                                                            \
    MFMA16(0, fa, fb2);         /* kh1 m0-3 */                                    \
    LGKM0;                      /* all reads of slot s landed */                  \
    BAR;                                                                          \
    STG_STMT;                   /* T+2 -> just-freed slot s */                    \
    GATE_STMT;                  /* T+1 resident (counted) */                      \
    BAR;                                                                          \
    RDB(o, 0, fb);              /* preload T+1 kh0 */                             \
    RDA(o, 0, 0, fa);                                                             \
    MFMA16(4, fa2, fb2);        /* kh1 m4-7 — hides the preload drain */          \
} while (0)

    #pragma unroll 1
    for (int j = 0; j < 4; ++j) {
        // zigzag within the 2x2 super-tile
        const int bm = sm * 2 + (j >> 1);
        const int bn = sn * 2 + ((j & 1) ^ (j >> 1));
        const char* Ab = A + (size_t)(bm * 256) * DIN;
        const char* Bb = Bw + (size_t)(bn * 256) * DIN;

        i32x4 acc[8][4] = {};
        i32x4 fa[4], fa2[4], fb[4], fb2[4];

        // prologue: all waves done reading previous j's LDS; stage T0,T1
        BAR;
        STGT(0, 0);
        STGT(128, 1);
        VM(8);                  // T0 resident (also drains prior j's stores)
        BAR;
        RDB(0, 0, fb);
        RDA(0, 0, 0, fa);

        #pragma unroll 1
        for (int it = 0; it < 7; ++it) {
            const int tB = it * 256;
            TILE(0, 1, STGT(tB + 256, 0), VM(8));
            TILE(1, 0, STGT(tB + 384, 1), VM(8));
        }
        // tile 14 (slot 0): nothing left to stage; full drain gates T15
        TILE(0, 1, (void)0, VM(0));
        // tile 15 (slot 1): straight-line, no barriers
        RDA(1, 0, 4, fa2);
        RDB(1, 1, fb2);
        MFMA16(0, fa, fb);
        RDA(1, 1, 0, fa);
        MFMA16(4, fa2, fb);
        RDA(1, 1, 4, fa2);
        MFMA16(0, fa, fb2);
        MFMA16(4, fa2, fb2);

        // epilogue: exact int32 -> fp32, dequant, store (fire and forget)
        const int c0 = bn * 256 + wn * 64 + lr;
        #pragma unroll
        for (int m = 0; m < 8; ++m) {
            #pragma unroll
            for (int r = 0; r < 4; ++r) {
                const int grow = bm * 256 + wm * 128 + m * 16 + lc * 4 + r;
                const float s = rowfac[grow] * wf;
                const size_t ob = (size_t)grow * DOUT + c0;
                #pragma unroll
                for (int n = 0; n < 4; ++n)
                    out[ob + n * 16] = (float)acc[m][n][r] * s;
            }
        }
    }
#undef STAGE
#undef STGT
#undef RDA
#undef RDB
#undef MFMA16
#undef LGKM0
#undef VM
#undef BAR
#undef TILE
}

extern "C" void kernel_launch(void* const* d_in, const int* in_sizes, int n_in,
                              void* d_out, int out_size, void* d_ws, size_t ws_size,
                              hipStream_t stream) {
    const float* x = (const float*)d_in[0];   // [4,2048,2048]
    const float* wt = (const float*)d_in[1];  // [8192,2048]
    float* out = (float*)d_out;               // [4,2048,8192] fp32
    char* ws = (char*)d_ws;

    double* part = (double*)(ws + WS_PART);
    float* wfac = (float*)(ws + WS_WFAC);
    float* rowfac = (float*)(ws + WS_ROWFAC);
    u32* xq = (u32*)(ws + WS_XQ);
    u32* wq = (u32*)(ws + WS_WQ);

    k_wabs<<<2048, 256, 0, stream>>>(wt, part);
    k_wfin<<<1, 256, 0, stream>>>(part, wfac);
    k_prep<<<2048 + MROWS, 256, 0, stream>>>(wt, wfac, wq, x, xq, rowfac);
    k_gemm<<<256, 512, 0, stream>>>((const char*)xq, (const char*)wq, rowfac, wfac, out);
}

// Round 11
// 213.804 us; speedup vs baseline: 1.0606x; 1.0606x over previous
//
#include <hip/hip_runtime.h>

typedef unsigned int u32;
typedef int i32x4 __attribute__((ext_vector_type(4)));

#define DIN 2048              // K elements; int8 row = 2048 bytes
#define DOUT 8192
#define MROWS 8192            // B*S
#define NELEM_W (8192 * 2048)

// workspace layout (bytes)
#define WS_PART 0                        // double[2048]
#define WS_WFAC 16384                    // float
#define WS_ROWFAC 16640                  // float[8192]
#define WS_XQ 49408                      // int8[8192*2048]
#define WS_WQ (49408 + 16777216)         // int8[8192*2048]

// ---------------- weight abs-sum (stage 1) ----------------------------------
__global__ void k_wabs(const float* __restrict__ w, double* __restrict__ part) {
    const float4* w4 = (const float4*)w;
    const unsigned t = threadIdx.x, b = blockIdx.x;
    float s = 0.f;
    for (unsigned i = b * 256u + t; i < (NELEM_W / 4); i += 2048u * 256u) {
        float4 v = w4[i];
        s += fabsf(v.x) + fabsf(v.y) + fabsf(v.z) + fabsf(v.w);
    }
    double d = (double)s;
    #pragma unroll
    for (int o = 32; o; o >>= 1) d += __shfl_down(d, o);
    __shared__ double red[4];
    if ((t & 63u) == 0u) red[t >> 6] = d;
    __syncthreads();
    if (t == 0) part[b] = red[0] + red[1] + red[2] + red[3];
}

// ---------------- weight abs-mean (stage 2) ---------------------------------
__global__ void k_wfin(const double* __restrict__ part, float* __restrict__ wfac) {
    const int t = threadIdx.x;
    double s = 0.0;
    #pragma unroll
    for (int j = 0; j < 8; ++j) s += part[t + j * 256];
    #pragma unroll
    for (int o = 32; o; o >>= 1) s += __shfl_down(s, o);
    __shared__ double red[4];
    if ((t & 63) == 0) red[t >> 6] = s;
    __syncthreads();
    if (t == 0) {
        double mean = (red[0] + red[1] + red[2] + red[3]) * (1.0 / (double)NELEM_W);
        *wfac = fmaxf((float)mean, 1e-5f);
    }
}

// ---------------- fused: ternary weight quant + RMS-norm/act quant ----------
__global__ void k_prep(const float* __restrict__ w, const float* __restrict__ wfac,
                       u32* __restrict__ wq, const float* __restrict__ x,
                       u32* __restrict__ xq, float* __restrict__ rowfac) {
    const int t = threadIdx.x;
    if (blockIdx.x < 2048) {
        const float scale = 1.0f / *wfac;
        const float4* w4 = (const float4*)w;
        for (unsigned i = blockIdx.x * 256u + t; i < (NELEM_W / 4); i += 2048u * 256u) {
            float4 v = w4[i];
            int q0 = (int)fminf(fmaxf(rintf(v.x * scale), -1.f), 1.f);
            int q1 = (int)fminf(fmaxf(rintf(v.y * scale), -1.f), 1.f);
            int q2 = (int)fminf(fmaxf(rintf(v.z * scale), -1.f), 1.f);
            int q3 = (int)fminf(fmaxf(rintf(v.w * scale), -1.f), 1.f);
            wq[i] = (u32)(q0 & 255) | ((u32)(q1 & 255) << 8) |
                    ((u32)(q2 & 255) << 16) | ((u32)(q3 & 255) << 24);
        }
        return;
    }
    const int row = blockIdx.x - 2048;
    const float4* xr = (const float4*)(x + (size_t)row * DIN);
    float4 v0 = xr[t], v1 = xr[t + 256];
    float ss = v0.x * v0.x + v0.y * v0.y + v0.z * v0.z + v0.w * v0.w
             + v1.x * v1.x + v1.y * v1.y + v1.z * v1.z + v1.w * v1.w;
    __shared__ float red[4];
    #pragma unroll
    for (int o = 32; o; o >>= 1) ss += __shfl_down(ss, o);
    if ((t & 63) == 0) red[t >> 6] = ss;
    __syncthreads();
    ss = red[0] + red[1] + red[2] + red[3];
    const float r = 1.0f / sqrtf(ss * (1.0f / DIN) + 1.1920929e-7f);
    float xn[8] = {v0.x * r, v0.y * r, v0.z * r, v0.w * r,
                   v1.x * r, v1.y * r, v1.z * r, v1.w * r};
    float am = 0.f;
    #pragma unroll
    for (int j = 0; j < 8; ++j) am = fmaxf(am, fabsf(xn[j]));
    __syncthreads();
    #pragma unroll
    for (int o = 32; o; o >>= 1) am = fmaxf(am, __shfl_down(am, o));
    if ((t & 63) == 0) red[t >> 6] = am;
    __syncthreads();
    am = fmaxf(fmaxf(red[0], red[1]), fmaxf(red[2], red[3]));
    const float amc = fmaxf(am, 1e-5f);
    const float s = 127.0f / amc;
    int q[8];
    #pragma unroll
    for (int j = 0; j < 8; ++j)
        q[j] = (int)fminf(fmaxf(rintf(xn[j] * s), -128.f), 127.f);
    u32* xo = xq + (size_t)row * (DIN / 4);
    xo[t] = (u32)(q[0] & 255) | ((u32)(q[1] & 255) << 8) |
            ((u32)(q[2] & 255) << 16) | ((u32)(q[3] & 255) << 24);
    xo[t + 256] = (u32)(q[4] & 255) | ((u32)(q[5] & 255) << 8) |
                  ((u32)(q[6] & 255) << 16) | ((u32)(q[7] & 255) << 24);
    if (t == 0) rowfac[row] = amc * (1.0f / 127.0f);
}

// ---------------- 256x128 int8 GEMM, 2 blocks/CU (16 waves/CU) ---------------
// C[m,n] = (sum_k Xq[m,k]*Wq[n,k]) * rowfac[m] * wfac.
// 8 waves (4M x 2N), wave tile 64x64 -> acc 64 + frag 32 regs; <=128 VGPR so
// TWO 512-thread blocks/CU (4 waves/SIMD): independent blocks desync, one
// block's MFMA fills the other's gate/barrier stalls (m114).
// LDS 48KB/block: A[2 slot][256][64B] @0 (slot 16384), B[2][128][64B] @32768
// (slot 8192). K-tile = 64 int8. r3's verified zero-conflict swizzle.
// Tile body (fixed r10 WAR bug): every frag's last MFMA use precedes reload:
//   LGKM0 (T's reads complete) ; BAR ; STG(T+2->s) ; VM(3) ; BAR ;
//   MFMA(m0-1) ; fa01<-T+1 ; MFMA(m2-3, old fb) ; fa23,fb<-T+1.
// The T+1 fb reads drain during the NEXT tile's VM gate (HBM wait) for free.
__launch_bounds__(512, 4)
__global__ void k_gemm(const char* __restrict__ A, const char* __restrict__ Bw,
                       const float* __restrict__ rowfac, const float* __restrict__ wfac,
                       float* __restrict__ out) {
    __shared__ __attribute__((aligned(16))) char smb[49152];

    const int t = threadIdx.x;
    const int l = t & 63, w = t >> 6;
    const int wm = w >> 1, wn = w & 1;
    const int lr = l & 15, lc = l >> 4;
    // verified zero-conflict read offset within a [rows][64B] buffer
    const int laneF = lr * 64 + ((lc ^ ((lr >> 1) & 3)) * 16);
    // staging: thread t writes LDS linear t*16 (row t>>2, phys granule t&3);
    // source logical granule = (t&3) ^ ((row>>1)&3) = (t&3) ^ ((t>>3)&3)
    const int srow = t >> 2;
    const int sgl = ((t & 3) ^ ((t >> 3) & 3)) * 16;

    // XCD-partitioned mapping: per XCD, 4 contiguous bm (A panels L2-resident),
    // bn sweeps 0..63. 2048 % 8 == 0 -> bijective.
    const int bid = blockIdx.x;
    const int g = (bid & 7) * 256 + (bid >> 3);
    const int bm = g >> 6, bn = g & 63;
    const char* Ab = A + (size_t)(bm * 256) * DIN;
    const char* Bb = Bw + (size_t)(bn * 128) * DIN;

    i32x4 acc[4][4] = {};          // [m][n], 64 regs
    i32x4 fb[4], fa01[2], fa23[2]; // 32 regs

// stage tile at byte-offset tB into slot s: A 2 loads + B 1 load per thread
#define STG(tB, s) do {                                                           \
    _Pragma("unroll")                                                             \
    for (int j_ = 0; j_ < 2; ++j_)                                                \
        __builtin_amdgcn_global_load_lds(                                         \
            (const __attribute__((address_space(1))) void*)(Ab + (size_t)(j_ * 128 + srow) * DIN + (tB) + sgl), \
            (__attribute__((address_space(3))) void*)(smb + (s) * 16384 + j_ * 8192 + t * 16), 16, 0, 0); \
    __builtin_amdgcn_global_load_lds(                                             \
        (const __attribute__((address_space(1))) void*)(Bb + (size_t)srow * DIN + (tB) + sgl), \
        (__attribute__((address_space(3))) void*)(smb + 32768 + (s) * 8192 + t * 16), 16, 0, 0); \
} while (0)

#define RDA(s, m_) (*(const i32x4*)(smb + (s) * 16384 + (wm * 64 + (m_) * 16) * 64 + laneF))
#define RDB(s, n_) (*(const i32x4*)(smb + 32768 + (s) * 8192 + (wn * 64 + (n_) * 16) * 64 + laneF))

#define MFMA_G(mB, fA) do {                                                       \
    __builtin_amdgcn_s_setprio(1);                                                \
    _Pragma("unroll")                                                             \
    for (int i_ = 0; i_ < 2; ++i_)                                                \
        _Pragma("unroll")                                                         \
        for (int n_ = 0; n_ < 4; ++n_)                                            \
            acc[(mB) + i_][n_] = __builtin_amdgcn_mfma_i32_16x16x64_i8(           \
                fA[i_], fb[n_], acc[(mB) + i_][n_], 0, 0, 0);                     \
    __builtin_amdgcn_s_setprio(0);                                                \
} while (0)

#define LGKM0 asm volatile("s_waitcnt lgkmcnt(0)" ::: "memory")
#define VM(n) asm volatile("s_waitcnt vmcnt(" #n ")" ::: "memory")
#define BAR __builtin_amdgcn_s_barrier()

// one K-tile T (slot s; T+1 in slot o). Entry: fb/fa01/fa23 = T's frags
// (reads issued at end of previous tile). All frag reloads are AFTER the
// last MFMA that reads the old value (SSA-safe, r10 bug fixed).
#define TILE(s, o, STG_STMT, GATE_STMT) do {                                      \
    LGKM0;                      /* T's 8 frag reads complete */                   \
    BAR;                        /* slot s free to overwrite */                    \
    STG_STMT;                   /* T+2 -> s */                                    \
    GATE_STMT;                  /* T+1 resident (counted) */                      \
    BAR;                                                                          \
    MFMA_G(0, fa01);            /* T m0-1 (uses old fb) */                        \
    fa01[0] = RDA(o, 0);                                                          \
    fa01[1] = RDA(o, 1);        /* T+1 A m0-1, hides under next MFMA */           \
    MFMA_G(2, fa23);            /* T m2-3 (old fb — last use) */                  \
    fa23[0] = RDA(o, 2);                                                          \
    fa23[1] = RDA(o, 3);                                                          \
    fb[0] = RDB(o, 0); fb[1] = RDB(o, 1);                                         \
    fb[2] = RDB(o, 2); fb[3] = RDB(o, 3);  /* drain under next VM gate */         \
} while (0)

    // prologue: stage T0->slot0, T1->slot1; gate T0; issue T0's frag reads
    STG(0, 0);
    STG(64, 1);
    VM(3);
    BAR;
    fb[0] = RDB(0, 0); fb[1] = RDB(0, 1); fb[2] = RDB(0, 2); fb[3] = RDB(0, 3);
    fa01[0] = RDA(0, 0); fa01[1] = RDA(0, 1);
    fa23[0] = RDA(0, 2); fa23[1] = RDA(0, 3);

    #pragma unroll 1
    for (int p = 0; p < 15; ++p) {        // tiles T=2p, T=2p+1  (T0..T29)
        const int tB = p * 128;
        TILE(0, 1, STG(tB + 128, 0), VM(3));
        TILE(1, 0, STG(tB + 192, 1), VM(3));
    }
    // T30 (slot 0): nothing to stage; VM(0) gates T31 (3 loads outstanding)
    TILE(0, 1, (void)0, VM(0));
    // T31 (slot 1): straight-line finish
    LGKM0;
    MFMA_G(0, fa01);
    MFMA_G(2, fa23);

    // epilogue: exact int32 -> fp32, dequant, store (fire and forget)
    const float wf = *wfac;
    const int c0 = bn * 128 + wn * 64 + lr;
    #pragma unroll
    for (int m = 0; m < 4; ++m) {
        #pragma unroll
        for (int r = 0; r < 4; ++r) {
            const int grow = bm * 256 + wm * 64 + m * 16 + lc * 4 + r;
            const float s = rowfac[grow] * wf;
            const size_t ob = (size_t)grow * DOUT + c0;
            #pragma unroll
            for (int n = 0; n < 4; ++n)
                out[ob + n * 16] = (float)acc[m][n][r] * s;
        }
    }
#undef STG
#undef RDA
#undef RDB
#undef MFMA_G
#undef LGKM0
#undef VM
#undef BAR
#undef TILE
}

extern "C" void kernel_launch(void* const* d_in, const int* in_sizes, int n_in,
                              void* d_out, int out_size, void* d_ws, size_t ws_size,
                              hipStream_t stream) {
    const float* x = (const float*)d_in[0];   // [4,2048,2048]
    const float* wt = (const float*)d_in[1];  // [8192,2048]
    float* out = (float*)d_out;               // [4,2048,8192] fp32
    char* ws = (char*)d_ws;

    double* part = (double*)(ws + WS_PART);
    float* wfac = (float*)(ws + WS_WFAC);
    float* rowfac = (float*)(ws + WS_ROWFAC);
    u32* xq = (u32*)(ws + WS_XQ);
    u32* wq = (u32*)(ws + WS_WQ);

    k_wabs<<<2048, 256, 0, stream>>>(wt, part);
    k_wfin<<<1, 256, 0, stream>>>(part, wfac);
    k_prep<<<2048 + MROWS, 256, 0, stream>>>(wt, wfac, wq, x, xq, rowfac);
    k_gemm<<<2048, 512, 0, stream>>>((const char*)xq, (const char*)wq, rowfac, wfac, out);
}